// Round 19
// baseline (306.331 us; speedup 1.0000x reference)
//
#include <hip/hip_runtime.h>
#include <hip/hip_bf16.h>

// C=96 D=192 K=4 N=16 R=6 B=8 H=W=64 L=4096 ; chunked scan: 64 chunks x 64 steps
// Split-correction scan: k4y one local scan -> y_loc + per-step S (bf16, tail-skipped);
// k4b chains chunk states; k4corr adds C·(e^{A·S}⊙h0) with wave-uniform early exit S>14.
// bf16 streams: yB, xc (u), lH, Sst, z, xp (conv input).

#define NCH 64
#define CLEN 64

typedef float v2f __attribute__((ext_vector_type(2)));
__device__ __forceinline__ v2f pkfma(v2f a, v2f b, v2f c){ return __builtin_elementwise_fma(a,b,c); }

__device__ __forceinline__ float sigm(float x){ return 1.f/(1.f+__expf(-x)); }
__device__ __forceinline__ float softplus_(float x){ return (x>20.f)? x : __logf(1.f+__expf(x)); }

__device__ __forceinline__ unsigned packbf2(float a, float b){
  __hip_bfloat16 ba = __float2bfloat16(a), bb = __float2bfloat16(b);
  unsigned short ua = *(unsigned short*)&ba, ub = *(unsigned short*)&bb;
  return (unsigned)ua | ((unsigned)ub<<16);
}
__device__ __forceinline__ float unpk_lo(unsigned u){ return __uint_as_float((u&0xffffu)<<16); }
__device__ __forceinline__ float unpk_hi(unsigned u){ return __uint_as_float(u&0xffff0000u); }

__device__ __forceinline__ void scan_p0dp2(int k, int v0, int& p0, int& dp){
  if(k==0){ p0 = v0; dp = 1; }
  else if(k==1){ p0 = ((v0&63)<<6)|(v0>>6); dp = 64; }
  else if(k==2){ p0 = 4095 - v0; dp = -1; }
  else { int m0 = 4095 - v0; p0 = ((m0&63)<<6)|(m0>>6); dp = -64; }
}

// ---------------- K0: weight transposes ----------------
__global__ __launch_bounds__(256) void k0_prep(
    const float* __restrict__ ipw, const float* __restrict__ xpw,
    const float* __restrict__ dtw, const float* __restrict__ opw,
    const float* __restrict__ pmw,
    float* __restrict__ ipwT, float* __restrict__ xpwTp,
    float* __restrict__ dtwT, float* __restrict__ opwT,
    float* __restrict__ pmwT)
{
  int g = blockIdx.x*256 + threadIdx.x;
  if(g < 36864){
    int c = g/384, n = g%384;
    ipwT[g] = ipw[n*96 + c];
  } else if(g < 67584){
    int t = g - 36864; int dd = t/160, n = t - dd*160; int k = n/40, c = n - k*40;
    float v;
    if(c < 6)       v = xpw[(k*38 + c)*192 + dd];
    else if(c < 8)  v = 0.f;
    else            v = xpw[(k*38 + (c-2))*192 + dd];
    xpwTp[t] = v;
  } else if(g < 72192){
    int t = g - 67584; int kr = t/192, d = t - kr*192; int k = kr/6, r = kr - k*6;
    dtwT[t] = dtw[(k*192 + d)*6 + r];
  } else if(g < 90624){
    int t = g - 72192; int d = t/96, c = t - d*96;
    opwT[t] = opw[c*192 + d];
  } else if(g < 164352){
    int t = g - 90624; int n = t/192, c2 = t - n*192;
    pmwT[t] = pmw[c2*384 + n];
  }
}

// ---------------- K1: LN1 + in_proj GEMM (+resid transpose), bf16 xp/z out ----------------
#define XT_PAD 68
__global__ __launch_bounds__(256) void k1_ln_inproj(
    const float* __restrict__ x, const float* __restrict__ lnw, const float* __restrict__ lnb,
    const float* __restrict__ ipwT, float* __restrict__ xT,
    __hip_bfloat16* __restrict__ xp, __hip_bfloat16* __restrict__ z)
{
  __shared__ float xt[96*XT_PAD];
  __shared__ float lnw_s[96], lnb_s[96], mu_s[64], rs_s[64];
  int tid = threadIdx.x;
  int mt = blockIdx.x, nt = blockIdx.y, b = blockIdx.z;
  int g0 = mt*64;
  const float* xb = x + (size_t)b*96*4096 + g0;
  for(int idx=tid; idx<6144; idx+=256){
    int c = idx>>6, p = idx&63;
    xt[c*XT_PAD+p] = xb[c*4096 + p];
  }
  if(tid<96){ lnw_s[tid]=lnw[tid]; lnb_s[tid]=lnb[tid]; }
  __syncthreads();
  if(nt==0){
    float* xTb = xT + ((size_t)(b*4096 + g0))*96;
    for(int idx=tid; idx<6144; idx+=256){
      int p = idx/96, c = idx - p*96;
      xTb[idx] = xt[c*XT_PAD+p];
    }
  }
  if(tid<64){
    float s=0.f,q=0.f;
    for(int c=0;c<96;c++){ float v=xt[c*XT_PAD+tid]; s+=v; q+=v*v; }
    float mu = s*(1.f/96.f);
    mu_s[tid]=mu; rs_s[tid]=rsqrtf(q*(1.f/96.f)-mu*mu+1e-5f);
  }
  __syncthreads();
  for(int idx=tid; idx<6144; idx+=256){
    int c = idx>>6, p = idx&63;
    int a = c*XT_PAD+p;
    xt[a] = (xt[a]-mu_s[p])*rs_s[p]*lnw_s[c]+lnb_s[c];
  }
  __syncthreads();
  int tm = tid>>5, tn = tid&31;
  float acc[8][4];
  #pragma unroll
  for(int i=0;i<8;i++){acc[i][0]=0.f;acc[i][1]=0.f;acc[i][2]=0.f;acc[i][3]=0.f;}
  const float* wbase = ipwT + nt*128 + tn*4;
  for(int kk=0;kk<96;kk++){
    float4 w4 = *(const float4*)(wbase + kk*384);
    float4 a0 = *(const float4*)&xt[kk*XT_PAD + tm*8];
    float4 a1 = *(const float4*)&xt[kk*XT_PAD + tm*8 + 4];
    float av[8]={a0.x,a0.y,a0.z,a0.w,a1.x,a1.y,a1.z,a1.w};
    #pragma unroll
    for(int i=0;i<8;i++){
      acc[i][0]=fmaf(av[i],w4.x,acc[i][0]);
      acc[i][1]=fmaf(av[i],w4.y,acc[i][1]);
      acc[i][2]=fmaf(av[i],w4.z,acc[i][2]);
      acc[i][3]=fmaf(av[i],w4.w,acc[i][3]);
    }
  }
  int n = nt*128 + tn*4;
  #pragma unroll
  for(int i=0;i<8;i++){
    size_t row = (size_t)(b*4096 + g0 + tm*8 + i);
    uint2 pz;
    pz.x = packbf2(acc[i][0],acc[i][1]);
    pz.y = packbf2(acc[i][2],acc[i][3]);
    if(n < 192) *(uint2*)(xp + row*192 + n) = pz;
    else        *(uint2*)(z  + row*192 + (n-192)) = pz;
  }
}

// ---------------- K2: depthwise 3x3 conv + bias + silu (2x8 tile), bf16 in/out ----------------
__global__ __launch_bounds__(192) void k2_conv(
    const __hip_bfloat16* __restrict__ xp, const float* __restrict__ cw, const float* __restrict__ cb,
    __hip_bfloat16* __restrict__ xc)
{
  __shared__ float cw_s[1728];
  int tid = threadIdx.x;
  int pq = blockIdx.x, b = blockIdx.y;
  for(int i=tid;i<1728;i+=192) cw_s[i]=cw[i];
  __syncthreads();
  int th = (pq>>3)<<1;
  int tw = (pq&7)<<3;
  const __hip_bfloat16* base = xp + (size_t)b*4096*192 + tid;
  const float* wp = &cw_s[tid*9];
  float bias = cb[tid];
  float acc[2][8];
  #pragma unroll
  for(int r=0;r<2;r++)
    #pragma unroll
    for(int j=0;j<8;j++) acc[r][j]=bias;
  #pragma unroll
  for(int iy=0; iy<4; iy++){
    int hh = th-1+iy;
    if(hh<0||hh>63) continue;
    float v[10];
    #pragma unroll
    for(int xx=0;xx<10;xx++){
      int ww = tw-1+xx;
      v[xx] = (ww>=0 && ww<64) ? __bfloat162float(base[((size_t)(hh*64+ww))*192]) : 0.f;
    }
    #pragma unroll
    for(int r=0;r<2;r++){
      int ky = iy - r;
      if(ky<0||ky>2) continue;
      float wk0=wp[ky*3], wk1=wp[ky*3+1], wk2=wp[ky*3+2];
      #pragma unroll
      for(int j=0;j<8;j++)
        acc[r][j] = fmaf(v[j],wk0, fmaf(v[j+1],wk1, fmaf(v[j+2],wk2, acc[r][j])));
    }
  }
  #pragma unroll
  for(int r=0;r<2;r++)
    #pragma unroll
    for(int j=0;j<8;j++){
      float a = acc[r][j];
      a = a * sigm(a);
      xc[((size_t)(b*4096) + (th+r)*64 + tw+j)*192 + tid] = __float2bfloat16(a);
    }
}

// ---------------- K3: x_proj GEMM (bf16 in via LDS) -> compact x_dbl ----------------
__global__ __launch_bounds__(320) void k3_proj(
    const __hip_bfloat16* __restrict__ xc, const float* __restrict__ xpwTp,
    float* __restrict__ xdbl)
{
  __shared__ float sm[32*192];
  int tid = threadIdx.x;
  int mt = blockIdx.x, b = blockIdx.y;
  int g0 = mt*32;
  const unsigned* xcb = (const unsigned*)(xc + ((size_t)(b*4096 + g0))*192);
  for(int idx=tid; idx<3072; idx+=320){
    unsigned u = xcb[idx];
    sm[idx*2]   = unpk_lo(u);
    sm[idx*2+1] = unpk_hi(u);
  }
  __syncthreads();
  int tn = tid%40, tm = tid/40;
  float acc[4][4];
  #pragma unroll
  for(int i=0;i<4;i++){acc[i][0]=0.f;acc[i][1]=0.f;acc[i][2]=0.f;acc[i][3]=0.f;}
  const float* wb = xpwTp + tn*4;
  for(int kk=0;kk<192;kk+=2){
    float4 w0 = *(const float4*)(wb + kk*160);
    float4 w1 = *(const float4*)(wb + (kk+1)*160);
    #pragma unroll
    for(int i=0;i<4;i++){
      float2 a = *(const float2*)&sm[(tm*4+i)*192 + kk];
      acc[i][0] = fmaf(a.x,w0.x, fmaf(a.y,w1.x, acc[i][0]));
      acc[i][1] = fmaf(a.x,w0.y, fmaf(a.y,w1.y, acc[i][1]));
      acc[i][2] = fmaf(a.x,w0.z, fmaf(a.y,w1.z, acc[i][2]));
      acc[i][3] = fmaf(a.x,w0.w, fmaf(a.y,w1.w, acc[i][3]));
    }
  }
  #pragma unroll
  for(int i=0;i<4;i++){
    *(float4*)(xdbl + ((size_t)(b*4096 + g0 + tm*4 + i))*160 + tn*4)
      = make_float4(acc[i][0],acc[i][1],acc[i][2],acc[i][3]);
  }
}

// ---------------- K4y: ONE local scan (h=0): y_loc + per-step S (tail-skipped) ----------------
__global__ __launch_bounds__(192) void k4y_scan(
    const float* __restrict__ xdbl, const __hip_bfloat16* __restrict__ xc,
    const float* __restrict__ alog, const float* __restrict__ dtwT,
    const float* __restrict__ dtb, const float* __restrict__ Dsv,
    __hip_bfloat16* __restrict__ yB, __hip_bfloat16* __restrict__ Sst,
    __hip_bfloat16* __restrict__ localH, float* __restrict__ Ssum)
{
  int d = threadIdx.x;
  int ch = blockIdx.x, k = blockIdx.y, b = blockIdx.z;
  size_t prow = (size_t)b*4096;
  int p0, dp;
  scan_p0dp2(k, ch*CLEN, p0, dp);
  const float* rowp = xdbl + (prow + (size_t)p0)*160 + k*40;   // block-uniform
  ptrdiff_t rstride = (ptrdiff_t)dp*160;
  float w0=dtwT[(k*6+0)*192+d], w1=dtwT[(k*6+1)*192+d], w2=dtwT[(k*6+2)*192+d],
        w3=dtwT[(k*6+3)*192+d], w4=dtwT[(k*6+4)*192+d], w5=dtwT[(k*6+5)*192+d];
  float dtbv = dtb[k*192+d];
  float A0; bool fast1;
  {
    const float4* ap = (const float4*)(alog + (size_t)(k*192+d)*16);
    float4 a0=ap[0],a1=ap[1],a2=ap[2],a3=ap[3];
    float t[16]={a0.x,a0.y,a0.z,a0.w,a1.x,a1.y,a1.z,a1.w,a2.x,a2.y,a2.z,a2.w,a3.x,a3.y,a3.z,a3.w};
    A0 = -__expf(t[0]);
    bool fast = true;
    #pragma unroll
    for(int n=1;n<16;n++)
      fast = fast && (fabsf(-__expf(t[n]) - (float)(n+1)*A0) <= 1e-4f*(float)(n+1)*fabsf(A0));
    fast1 = fast && (A0 == -1.0f);
  }
  float dsv = Dsv[k*192+d];
  float S=0.f;
  const __hip_bfloat16* xu = xc + (prow + (size_t)p0)*192 + d;
  ptrdiff_t ustride = (ptrdiff_t)dp*192;
  size_t strm = (((size_t)(b*4+k))*4096 + ch*CLEN)*192 + d;
  __hip_bfloat16* yP = yB + strm;
  __hip_bfloat16* SP = Sst + strm;
  unsigned* lh = (unsigned*)(localH + ((((size_t)(b*4+k))*NCH + ch)*192 + d)*16);
  if(fast1){
    v2f h01={0.f,0.f},h23={0.f,0.f},h45={0.f,0.f},h67={0.f,0.f},
        h89={0.f,0.f},hAB={0.f,0.f},hCD={0.f,0.f},hEF={0.f,0.f};
    bool sdone = false;
    for(int i=0;i<CLEN;i++){
      const float* row = rowp; rowp += rstride;
      float u = __bfloat162float(*xu); xu += ustride;
      float4 r03 = *(const float4*)row;
      float2 r45 = *(const float2*)(row+4);
      float p01 = fmaf(r03.y,w1, r03.x*w0);
      float p23 = fmaf(r03.w,w3, r03.z*w2);
      float p45 = fmaf(r45.y,w5, r45.x*w4);
      float raw = (dtbv + p01) + (p23 + p45);
      float ex = __expf(raw);
      float tt = 1.f + ex;
      float delta = (raw>20.f)? raw : __logf(tt);
      float e1 = __builtin_amdgcn_rcpf(tt);     // e^{-delta} since A0=-1
      float du = delta*u;
      S += delta;
      __hip_bfloat16 sb = __float2bfloat16(S);
      if(!sdone) SP[(size_t)i*192] = sb;        // stores through first all-true step
      sdone = sdone || (bool)__all(__bfloat162float(sb) > 14.f);
      float4 B0=*(const float4*)(row+8),  B1=*(const float4*)(row+12),
             B2=*(const float4*)(row+16), B3=*(const float4*)(row+20);
      float4 C0=*(const float4*)(row+24), C1=*(const float4*)(row+28),
             C2=*(const float4*)(row+32), C3=*(const float4*)(row+36);
      float e2s = e1*e1;
      v2f e2v = {e2s,e2s};
      v2f e4v = e2v*e2v;
      v2f e8v = e4v*e4v;
      v2f c01 = {e1,e2s};
      v2f c23 = c01*e2v;
      v2f c45 = c01*e4v;
      v2f c67 = c23*e4v;
      v2f c89 = c01*e8v;
      v2f cAB = c23*e8v;
      v2f cCD = c45*e8v;
      v2f cEF = c67*e8v;
      v2f du2 = {du,du};
      h01 = pkfma(h01,c01, du2*(v2f){B0.x,B0.y});
      h23 = pkfma(h23,c23, du2*(v2f){B0.z,B0.w});
      h45 = pkfma(h45,c45, du2*(v2f){B1.x,B1.y});
      h67 = pkfma(h67,c67, du2*(v2f){B1.z,B1.w});
      h89 = pkfma(h89,c89, du2*(v2f){B2.x,B2.y});
      hAB = pkfma(hAB,cAB, du2*(v2f){B2.z,B2.w});
      hCD = pkfma(hCD,cCD, du2*(v2f){B3.x,B3.y});
      hEF = pkfma(hEF,cEF, du2*(v2f){B3.z,B3.w});
      v2f yv = h01*(v2f){C0.x,C0.y};
      yv = pkfma(h23,(v2f){C0.z,C0.w}, yv);
      yv = pkfma(h45,(v2f){C1.x,C1.y}, yv);
      yv = pkfma(h67,(v2f){C1.z,C1.w}, yv);
      yv = pkfma(h89,(v2f){C2.x,C2.y}, yv);
      yv = pkfma(hAB,(v2f){C2.z,C2.w}, yv);
      yv = pkfma(hCD,(v2f){C3.x,C3.y}, yv);
      yv = pkfma(hEF,(v2f){C3.z,C3.w}, yv);
      yP[(size_t)i*192] = __float2bfloat16(fmaf(dsv, u, yv.x + yv.y));
    }
    uint4 q0, q1;
    q0.x = packbf2(h01.x,h01.y); q0.y = packbf2(h23.x,h23.y);
    q0.z = packbf2(h45.x,h45.y); q0.w = packbf2(h67.x,h67.y);
    q1.x = packbf2(h89.x,h89.y); q1.y = packbf2(hAB.x,hAB.y);
    q1.z = packbf2(hCD.x,hCD.y); q1.w = packbf2(hEF.x,hEF.y);
    *(uint4*)lh = q0;
    *(uint4*)(lh+4) = q1;
  } else {
    float A[16], h[16];
    {
      const float4* ap = (const float4*)(alog + (size_t)(k*192+d)*16);
      float4 a0=ap[0],a1=ap[1],a2=ap[2],a3=ap[3];
      float t[16]={a0.x,a0.y,a0.z,a0.w,a1.x,a1.y,a1.z,a1.w,a2.x,a2.y,a2.z,a2.w,a3.x,a3.y,a3.z,a3.w};
      #pragma unroll
      for(int n=0;n<16;n++){ A[n] = -__expf(t[n]); h[n]=0.f; }
    }
    for(int i=0;i<CLEN;i++){
      const float* row = rowp; rowp += rstride;
      float u = __bfloat162float(*xu); xu += ustride;
      float p01 = fmaf(row[1],w1, row[0]*w0);
      float p23 = fmaf(row[3],w3, row[2]*w2);
      float p45 = fmaf(row[5],w5, row[4]*w4);
      float delta = softplus_((dtbv + p01) + (p23 + p45));
      float du = delta*u;
      S += delta;
      SP[(size_t)i*192] = __float2bfloat16(S);
      float4 B0=*(const float4*)(row+8),  B1=*(const float4*)(row+12),
             B2=*(const float4*)(row+16), B3=*(const float4*)(row+20);
      float Bn[16]={B0.x,B0.y,B0.z,B0.w,B1.x,B1.y,B1.z,B1.w,
                    B2.x,B2.y,B2.z,B2.w,B3.x,B3.y,B3.z,B3.w};
      float4 C0=*(const float4*)(row+24), C1=*(const float4*)(row+28),
             C2=*(const float4*)(row+32), C3=*(const float4*)(row+36);
      float Cn[16]={C0.x,C0.y,C0.z,C0.w,C1.x,C1.y,C1.z,C1.w,
                    C2.x,C2.y,C2.z,C2.w,C3.x,C3.y,C3.z,C3.w};
      float y = 0.f;
      #pragma unroll
      for(int n=0;n<16;n++){
        h[n] = fmaf(h[n], __expf(delta*A[n]), du*Bn[n]);
        y = fmaf(h[n], Cn[n], y);
      }
      yP[(size_t)i*192] = __float2bfloat16(fmaf(dsv, u, y));
    }
    uint4 q0, q1;
    q0.x = packbf2(h[0],h[1]);   q0.y = packbf2(h[2],h[3]);
    q0.z = packbf2(h[4],h[5]);   q0.w = packbf2(h[6],h[7]);
    q1.x = packbf2(h[8],h[9]);   q1.y = packbf2(h[10],h[11]);
    q1.z = packbf2(h[12],h[13]); q1.w = packbf2(h[14],h[15]);
    *(uint4*)lh = q0;
    *(uint4*)(lh+4) = q1;
  }
  Ssum[(((size_t)(b*4+k))*NCH + ch)*192 + d] = S;
}

// ---------------- K4b: chain chunk states (bf16 lH; fp32 chain in regs) ----------------
__global__ __launch_bounds__(256) void k4b_chain(
    __hip_bfloat16* __restrict__ localH, const float* __restrict__ Ssum,
    const float* __restrict__ alog)
{
  int g = blockIdx.x*256 + threadIdx.x;   // 98304 = 32 bk * 3072 dn
  int bk = g/3072, dn = g - bk*3072;
  int k = bk & 3;
  int d = dn>>4, n = dn&15;
  float A = -__expf(alog[((size_t)(k*192+d))*16 + n]);
  size_t hbase = (size_t)bk*NCH*3072 + dn;
  size_t sbase = (size_t)bk*NCH*192 + d;
  float hv = 0.f;
  float loc = __bfloat162float(localH[hbase]);
  float S   = Ssum[sbase];
  for(int ch=0; ch<NCH; ch++){
    float nloc = 0.f, nS = 0.f;
    if(ch < NCH-1){
      nloc = __bfloat162float(localH[hbase + (size_t)(ch+1)*3072]);
      nS   = Ssum[sbase + (size_t)(ch+1)*192];
    }
    float dec = __expf(A*S);
    localH[hbase + (size_t)ch*3072] = __float2bfloat16(hv);
    hv = fmaf(hv, dec, loc);
    loc = nloc; S = nS;
  }
}

// ---------------- K4corr: y += C·(e^{A·S} ⊙ h0)  (skips chunk 0; early exit S>14) ----------------
__global__ __launch_bounds__(192) void k4corr(
    const float* __restrict__ xdbl, const float* __restrict__ alog,
    const __hip_bfloat16* __restrict__ hin, const __hip_bfloat16* __restrict__ Sst,
    __hip_bfloat16* __restrict__ yB)
{
  int d = threadIdx.x;
  int ch = blockIdx.x + 1, k = blockIdx.y, b = blockIdx.z;
  size_t prow = (size_t)b*4096;
  int p0, dp;
  scan_p0dp2(k, ch*CLEN, p0, dp);
  const float* rowp = xdbl + (prow + (size_t)p0)*160 + k*40 + 24;  // C base, uniform
  ptrdiff_t rstride = (ptrdiff_t)dp*160;
  float A0; bool fast1;
  {
    const float4* ap = (const float4*)(alog + (size_t)(k*192+d)*16);
    float4 a0=ap[0],a1=ap[1],a2=ap[2],a3=ap[3];
    float t[16]={a0.x,a0.y,a0.z,a0.w,a1.x,a1.y,a1.z,a1.w,a2.x,a2.y,a2.z,a2.w,a3.x,a3.y,a3.z,a3.w};
    A0 = -__expf(t[0]);
    bool fast = true;
    #pragma unroll
    for(int n=1;n<16;n++)
      fast = fast && (fabsf(-__expf(t[n]) - (float)(n+1)*A0) <= 1e-4f*(float)(n+1)*fabsf(A0));
    fast1 = fast && (A0 == -1.0f);
  }
  const unsigned* hp = (const unsigned*)(hin + ((((size_t)(b*4+k))*NCH + ch)*192 + d)*16);
  uint4 q0 = *(const uint4*)hp;
  uint4 q1 = *(const uint4*)(hp+4);
  size_t strm = (((size_t)(b*4+k))*4096 + ch*CLEN)*192 + d;
  const __hip_bfloat16* SP = Sst + strm;
  __hip_bfloat16* yP = yB + strm;
  if(fast1){
    v2f t01={unpk_lo(q0.x),unpk_hi(q0.x)}, t23={unpk_lo(q0.y),unpk_hi(q0.y)},
        t45={unpk_lo(q0.z),unpk_hi(q0.z)}, t67={unpk_lo(q0.w),unpk_hi(q0.w)},
        t89={unpk_lo(q1.x),unpk_hi(q1.x)}, tAB={unpk_lo(q1.y),unpk_hi(q1.y)},
        tCD={unpk_lo(q1.z),unpk_hi(q1.z)}, tEF={unpk_lo(q1.w),unpk_hi(q1.w)};
    for(int i=0;i<CLEN;i++){
      const float* row = rowp; rowp += rstride;
      float S = __bfloat162float(SP[(size_t)i*192]);
      if(__all(S > 14.f)) break;     // remaining corr < 1e-5, below bf16-y quantum
      float g = __expf(-S);
      float4 C0=*(const float4*)row,     C1=*(const float4*)(row+4),
             C2=*(const float4*)(row+8), C3=*(const float4*)(row+12);
      float g2s = g*g;
      v2f g2v = {g2s,g2s};
      v2f g4v = g2v*g2v;
      v2f g8v = g4v*g4v;
      v2f c01 = {g,g2s};
      v2f c23 = c01*g2v;
      v2f c45 = c01*g4v;
      v2f c67 = c23*g4v;
      v2f c89 = c01*g8v;
      v2f cAB = c23*g8v;
      v2f cCD = c45*g8v;
      v2f cEF = c67*g8v;
      v2f acc = t01*(c01*(v2f){C0.x,C0.y});
      acc = pkfma(t23, c23*(v2f){C0.z,C0.w}, acc);
      acc = pkfma(t45, c45*(v2f){C1.x,C1.y}, acc);
      acc = pkfma(t67, c67*(v2f){C1.z,C1.w}, acc);
      acc = pkfma(t89, c89*(v2f){C2.x,C2.y}, acc);
      acc = pkfma(tAB, cAB*(v2f){C2.z,C2.w}, acc);
      acc = pkfma(tCD, cCD*(v2f){C3.x,C3.y}, acc);
      acc = pkfma(tEF, cEF*(v2f){C3.z,C3.w}, acc);
      float corr = acc.x + acc.y;
      yP[(size_t)i*192] =
        __float2bfloat16(__bfloat162float(yP[(size_t)i*192]) + corr);
    }
  } else {
    float A[16], t[16];
    {
      const float4* ap = (const float4*)(alog + (size_t)(k*192+d)*16);
      float4 a0=ap[0],a1=ap[1],a2=ap[2],a3=ap[3];
      float tt[16]={a0.x,a0.y,a0.z,a0.w,a1.x,a1.y,a1.z,a1.w,a2.x,a2.y,a2.z,a2.w,a3.x,a3.y,a3.z,a3.w};
      #pragma unroll
      for(int n=0;n<16;n++) A[n] = -__expf(tt[n]);
    }
    t[0]=unpk_lo(q0.x); t[1]=unpk_hi(q0.x); t[2]=unpk_lo(q0.y); t[3]=unpk_hi(q0.y);
    t[4]=unpk_lo(q0.z); t[5]=unpk_hi(q0.z); t[6]=unpk_lo(q0.w); t[7]=unpk_hi(q0.w);
    t[8]=unpk_lo(q1.x); t[9]=unpk_hi(q1.x); t[10]=unpk_lo(q1.y); t[11]=unpk_hi(q1.y);
    t[12]=unpk_lo(q1.z); t[13]=unpk_hi(q1.z); t[14]=unpk_lo(q1.w); t[15]=unpk_hi(q1.w);
    for(int i=0;i<CLEN;i++){
      const float* row = rowp; rowp += rstride;
      float S = __bfloat162float(SP[(size_t)i*192]);
      float corr = 0.f;
      #pragma unroll
      for(int n=0;n<16;n++)
        corr = fmaf(t[n]*row[n], __expf(A[n]*S), corr);
      yP[(size_t)i*192] =
        __float2bfloat16(__bfloat162float(yP[(size_t)i*192]) + corr);
    }
  }
}

// ---------------- K5: combine + out_norm + silu(z) + out_proj + resid ----------------
#define YPAD 193
__global__ __launch_bounds__(256) void k5_combine(
    const __hip_bfloat16* __restrict__ yS, const __hip_bfloat16* __restrict__ z,
    const float* __restrict__ xT,
    const float* __restrict__ onw, const float* __restrict__ onb,
    const float* __restrict__ opwT, float* __restrict__ out_pre)
{
  __shared__ float yn[64*YPAD];
  __shared__ float wsm[48*96];
  __shared__ float mu_s[64], rs_s[64];
  int tid = threadIdx.x;
  int mt = blockIdx.x, b = blockIdx.y;
  int g0 = mt*64;
  size_t base = (size_t)b*4*4096;
  for(int idx=tid; idx<12288; idx+=256){
    int p = idx/192, d = idx - p*192;
    int gp = g0 + p;
    int l1 = ((gp&63)<<6)|(gp>>6);
    float v = __bfloat162float(yS[(base + gp)*192 + d])
            + __bfloat162float(yS[(base + 4096 + l1)*192 + d])
            + __bfloat162float(yS[(base + 2*4096 + (4095-gp))*192 + d])
            + __bfloat162float(yS[(base + 3*4096 + (4095-l1))*192 + d]);
    yn[p*YPAD+d] = v;
  }
  __syncthreads();
  {
    int p = tid>>2, q = tid&3;
    float s=0.f, sq=0.f;
    for(int c=q;c<192;c+=4){ float v=yn[p*YPAD+c]; s+=v; sq=fmaf(v,v,sq); }
    s  += __shfl_xor(s,1);  sq += __shfl_xor(sq,1);
    s  += __shfl_xor(s,2);  sq += __shfl_xor(sq,2);
    if(q==0){
      float mu = s*(1.f/192.f);
      mu_s[p]=mu; rs_s[p]=rsqrtf(sq*(1.f/192.f)-mu*mu+1e-5f);
    }
  }
  __syncthreads();
  for(int idx=tid; idx<12288; idx+=256){
    int p = idx/192, d = idx - p*192;
    float zz = __bfloat162float(z[((size_t)(b*4096+g0+p))*192 + d]);
    float v = (yn[p*YPAD+d]-mu_s[p])*rs_s[p]*onw[d]+onb[d];
    yn[p*YPAD+d] = v * zz * sigm(zz);
  }
  __syncthreads();
  int tn = tid&15, tm = tid>>4;
  float acc[4][6];
  #pragma unroll
  for(int i=0;i<4;i++)
    #pragma unroll
    for(int j=0;j<6;j++) acc[i][j]=0.f;
  for(int kc=0; kc<4; kc++){
    for(int idx=tid; idx<4608; idx+=256) wsm[idx] = opwT[kc*4608 + idx];
    __syncthreads();
    for(int kk=0;kk<48;kk++){
      float a0 = yn[(tm*4+0)*YPAD + kc*48+kk];
      float a1 = yn[(tm*4+1)*YPAD + kc*48+kk];
      float a2 = yn[(tm*4+2)*YPAD + kc*48+kk];
      float a3 = yn[(tm*4+3)*YPAD + kc*48+kk];
      const float* wr = &wsm[kk*96 + tn*6];
      #pragma unroll
      for(int j=0;j<6;j++){
        float w = wr[j];
        acc[0][j]=fmaf(a0,w,acc[0][j]);
        acc[1][j]=fmaf(a1,w,acc[1][j]);
        acc[2][j]=fmaf(a2,w,acc[2][j]);
        acc[3][j]=fmaf(a3,w,acc[3][j]);
      }
    }
    __syncthreads();
  }
  #pragma unroll
  for(int i=0;i<4;i++){
    size_t row = (size_t)(b*4096 + g0 + tm*4 + i);
    const float* xr = xT + row*96 + tn*6;
    float* orr = out_pre + row*96 + tn*6;
    #pragma unroll
    for(int j=0;j<6;j++) orr[j] = acc[i][j] + xr[j];
  }
}

// ---------------- K6: patch merge + LN + pm_red ----------------
__global__ __launch_bounds__(192) void k6_pm(
    const float* __restrict__ out_pre, const float* __restrict__ pmw, const float* __restrict__ pmb,
    const float* __restrict__ pmwT, float* __restrict__ outp)
{
  __shared__ float xm[8*388];
  __shared__ float xo[8*193];
  __shared__ float mus[8], rss[8];
  int tid = threadIdx.x;
  int jt = blockIdx.x, i = blockIdx.y, b = blockIdx.z;
  for(int idx=tid; idx<3072; idx+=192){
    int pj = idx/384, n = idx - pj*384;
    int q = n/96, c = n - q*96;
    int j = jt*8 + pj;
    int h2 = 2*i + (q&1), w2 = 2*j + (q>>1);
    xm[pj*388+n] = out_pre[((size_t)b*4096 + h2*64 + w2)*96 + c];
  }
  __syncthreads();
  if(tid<8){
    float s=0.f,q=0.f;
    for(int n=0;n<384;n++){ float v=xm[tid*388+n]; s+=v; q+=v*v; }
    float mu=s*(1.f/384.f);
    mus[tid]=mu; rss[tid]=rsqrtf(q*(1.f/384.f)-mu*mu+1e-5f);
  }
  __syncthreads();
  for(int idx=tid; idx<3072; idx+=192){
    int pj = idx/384, n = idx - pj*384;
    xm[pj*388+n] = (xm[pj*388+n]-mus[pj])*rss[pj]*pmw[n]+pmb[n];
  }
  __syncthreads();
  float acc[8];
  #pragma unroll
  for(int pj=0;pj<8;pj++) acc[pj]=0.f;
  const float* wb = pmwT + tid;
  for(int n4=0;n4<96;n4++){
    float w0=wb[(n4*4+0)*192], w1=wb[(n4*4+1)*192], w2=wb[(n4*4+2)*192], w3=wb[(n4*4+3)*192];
    #pragma unroll
    for(int pj=0;pj<8;pj++){
      float4 v = *(const float4*)&xm[pj*388 + n4*4];
      acc[pj] = fmaf(v.x,w0,fmaf(v.y,w1,fmaf(v.z,w2,fmaf(v.w,w3,acc[pj]))));
    }
  }
  #pragma unroll
  for(int pj=0;pj<8;pj++) xo[pj*193+tid]=acc[pj];
  __syncthreads();
  for(int idx=tid; idx<1536; idx+=192){
    int c2 = idx>>3, pj = idx&7;
    outp[(((size_t)b*192 + c2)*32 + i)*32 + jt*8 + pj] = xo[pj*193+c2];
  }
}

extern "C" void kernel_launch(void* const* d_in, const int* in_sizes, int n_in,
                              void* d_out, int out_size, void* d_ws, size_t ws_size,
                              hipStream_t stream)
{
  const float* x    = (const float*)d_in[0];
  const float* lnw  = (const float*)d_in[1];
  const float* lnb  = (const float*)d_in[2];
  const float* ipw  = (const float*)d_in[3];
  const float* cw   = (const float*)d_in[4];
  const float* cb   = (const float*)d_in[5];
  const float* xpw  = (const float*)d_in[6];
  const float* dtw  = (const float*)d_in[7];
  const float* dtb  = (const float*)d_in[8];
  const float* alog = (const float*)d_in[9];
  const float* Dsv  = (const float*)d_in[10];
  const float* onw  = (const float*)d_in[11];
  const float* onb  = (const float*)d_in[12];
  const float* opw  = (const float*)d_in[13];
  const float* pmnw = (const float*)d_in[14];
  const float* pmnb = (const float*)d_in[15];
  const float* pmrw = (const float*)d_in[16];
  float* out = (float*)d_out;

  float* ws    = (float*)d_ws;
  float* xT    = ws;              // (B,L,96)    3,145,728 f
  float* xpb   = xT + 3145728;    // 6,291,456 f region; aliased: xp bf16 (k1..k2), xdbl fp32 (k3..k4corr), out_pre (k5..k6)
  float* zbf   = xpb + 6291456;   // (B,L,192) bf16 -> 3,145,728 f-slots
  float* xcf   = zbf + 3145728;   // (B,L,192) bf16 -> 3,145,728 f-slots
  float* yBf   = xcf + 3145728;   // (B,K,L,192) bf16 -> 12,582,912 f-slots
  float* Sstf  = yBf + 12582912;  // (B,K,L,192) bf16 -> 12,582,912 f-slots
  float* lHf   = Sstf + 12582912; // (B,K,NCH,192,16) bf16 -> 3,145,728 f-slots
  float* Ss    = lHf + 3145728;   // (B,K,NCH,192)      393,216 f
  float* ipwT  = Ss + 393216;     // 36864
  float* xpwTp = ipwT + 36864;    // 30720
  float* dtwT  = xpwTp + 30720;   // 4608
  float* opwT  = dtwT + 4608;     // 18432
  float* pmwT  = opwT + 18432;    // 73728  -> total ~174 MiB
  float* xdbl  = xpb;             // (B,L,160) fp32 alias (xp-bf16 dead after k2... k3 writes over)
  float* outp  = xpb;             // out_pre alias (xdbl dead after k4corr)
  __hip_bfloat16* xpB = (__hip_bfloat16*)xpb;
  __hip_bfloat16* zb  = (__hip_bfloat16*)zbf;
  __hip_bfloat16* xc  = (__hip_bfloat16*)xcf;
  __hip_bfloat16* yB  = (__hip_bfloat16*)yBf;
  __hip_bfloat16* Sst = (__hip_bfloat16*)Sstf;
  __hip_bfloat16* lH  = (__hip_bfloat16*)lHf;

  k0_prep      <<<dim3(642),       dim3(256), 0, stream>>>(ipw,xpw,dtw,opw,pmrw, ipwT,xpwTp,dtwT,opwT,pmwT);
  k1_ln_inproj <<<dim3(64,3,8),    dim3(256), 0, stream>>>(x,lnw,lnb,ipwT, xT,xpB,zb);
  k2_conv      <<<dim3(256,8),     dim3(192), 0, stream>>>(xpB,cw,cb, xc);
  k3_proj      <<<dim3(128,8),     dim3(320), 0, stream>>>(xc,xpwTp, xdbl);
  k4y_scan     <<<dim3(NCH,4,8),   dim3(192), 0, stream>>>(xdbl,xc,alog,dtwT,dtb,Dsv, yB,Sst,lH,Ss);
  k4b_chain    <<<dim3(384),       dim3(256), 0, stream>>>(lH,Ss,alog);
  k4corr       <<<dim3(NCH-1,4,8), dim3(192), 0, stream>>>(xdbl,alog,lH,Sst, yB);
  k5_combine   <<<dim3(64,8),      dim3(256), 0, stream>>>(yB,zb,xT,onw,onb,opwT, outp);
  k6_pm        <<<dim3(4,32,8),    dim3(192), 0, stream>>>(outp,pmnw,pmnb,pmwT, out);
}

// Round 20
// 299.140 us; speedup vs baseline: 1.0240x; 1.0240x over previous
//
#include <hip/hip_runtime.h>
#include <hip/hip_bf16.h>

// C=96 D=192 K=4 N=16 R=6 B=8 H=W=64 L=4096 ; chunked scan: 64 chunks x 64 steps
// Split-correction scan: k4y one local scan -> y_loc + per-step S (bf16);
// k4b chains chunk states; k4corr adds C·(e^{A·S}⊙h0) with wave-uniform early exit S>14.
// bf16 streams: yB, xc (u), lH, Sst, z.  (R18-proven 299.5us configuration.)

#define NCH 64
#define CLEN 64

typedef float v2f __attribute__((ext_vector_type(2)));
__device__ __forceinline__ v2f pkfma(v2f a, v2f b, v2f c){ return __builtin_elementwise_fma(a,b,c); }

__device__ __forceinline__ float sigm(float x){ return 1.f/(1.f+__expf(-x)); }
__device__ __forceinline__ float softplus_(float x){ return (x>20.f)? x : __logf(1.f+__expf(x)); }

__device__ __forceinline__ unsigned packbf2(float a, float b){
  __hip_bfloat16 ba = __float2bfloat16(a), bb = __float2bfloat16(b);
  unsigned short ua = *(unsigned short*)&ba, ub = *(unsigned short*)&bb;
  return (unsigned)ua | ((unsigned)ub<<16);
}
__device__ __forceinline__ float unpk_lo(unsigned u){ return __uint_as_float((u&0xffffu)<<16); }
__device__ __forceinline__ float unpk_hi(unsigned u){ return __uint_as_float(u&0xffff0000u); }

__device__ __forceinline__ void scan_p0dp2(int k, int v0, int& p0, int& dp){
  if(k==0){ p0 = v0; dp = 1; }
  else if(k==1){ p0 = ((v0&63)<<6)|(v0>>6); dp = 64; }
  else if(k==2){ p0 = 4095 - v0; dp = -1; }
  else { int m0 = 4095 - v0; p0 = ((m0&63)<<6)|(m0>>6); dp = -64; }
}

// ---------------- K0: weight transposes ----------------
__global__ __launch_bounds__(256) void k0_prep(
    const float* __restrict__ ipw, const float* __restrict__ xpw,
    const float* __restrict__ dtw, const float* __restrict__ opw,
    const float* __restrict__ pmw,
    float* __restrict__ ipwT, float* __restrict__ xpwTp,
    float* __restrict__ dtwT, float* __restrict__ opwT,
    float* __restrict__ pmwT)
{
  int g = blockIdx.x*256 + threadIdx.x;
  if(g < 36864){
    int c = g/384, n = g%384;
    ipwT[g] = ipw[n*96 + c];
  } else if(g < 67584){
    int t = g - 36864; int dd = t/160, n = t - dd*160; int k = n/40, c = n - k*40;
    float v;
    if(c < 6)       v = xpw[(k*38 + c)*192 + dd];
    else if(c < 8)  v = 0.f;
    else            v = xpw[(k*38 + (c-2))*192 + dd];
    xpwTp[t] = v;
  } else if(g < 72192){
    int t = g - 67584; int kr = t/192, d = t - kr*192; int k = kr/6, r = kr - k*6;
    dtwT[t] = dtw[(k*192 + d)*6 + r];
  } else if(g < 90624){
    int t = g - 72192; int d = t/96, c = t - d*96;
    opwT[t] = opw[c*192 + d];
  } else if(g < 164352){
    int t = g - 90624; int n = t/192, c2 = t - n*192;
    pmwT[t] = pmw[c2*384 + n];
  }
}

// ---------------- K1: LN1 + in_proj GEMM (+resid transpose), bf16 z out ----------------
#define XT_PAD 68
__global__ __launch_bounds__(256) void k1_ln_inproj(
    const float* __restrict__ x, const float* __restrict__ lnw, const float* __restrict__ lnb,
    const float* __restrict__ ipwT, float* __restrict__ xT,
    float* __restrict__ xp, __hip_bfloat16* __restrict__ z)
{
  __shared__ float xt[96*XT_PAD];
  __shared__ float lnw_s[96], lnb_s[96], mu_s[64], rs_s[64];
  int tid = threadIdx.x;
  int mt = blockIdx.x, nt = blockIdx.y, b = blockIdx.z;
  int g0 = mt*64;
  const float* xb = x + (size_t)b*96*4096 + g0;
  for(int idx=tid; idx<6144; idx+=256){
    int c = idx>>6, p = idx&63;
    xt[c*XT_PAD+p] = xb[c*4096 + p];
  }
  if(tid<96){ lnw_s[tid]=lnw[tid]; lnb_s[tid]=lnb[tid]; }
  __syncthreads();
  if(nt==0){
    float* xTb = xT + ((size_t)(b*4096 + g0))*96;
    for(int idx=tid; idx<6144; idx+=256){
      int p = idx/96, c = idx - p*96;
      xTb[idx] = xt[c*XT_PAD+p];
    }
  }
  if(tid<64){
    float s=0.f,q=0.f;
    for(int c=0;c<96;c++){ float v=xt[c*XT_PAD+tid]; s+=v; q+=v*v; }
    float mu = s*(1.f/96.f);
    mu_s[tid]=mu; rs_s[tid]=rsqrtf(q*(1.f/96.f)-mu*mu+1e-5f);
  }
  __syncthreads();
  for(int idx=tid; idx<6144; idx+=256){
    int c = idx>>6, p = idx&63;
    int a = c*XT_PAD+p;
    xt[a] = (xt[a]-mu_s[p])*rs_s[p]*lnw_s[c]+lnb_s[c];
  }
  __syncthreads();
  int tm = tid>>5, tn = tid&31;
  float acc[8][4];
  #pragma unroll
  for(int i=0;i<8;i++){acc[i][0]=0.f;acc[i][1]=0.f;acc[i][2]=0.f;acc[i][3]=0.f;}
  const float* wbase = ipwT + nt*128 + tn*4;
  for(int kk=0;kk<96;kk++){
    float4 w4 = *(const float4*)(wbase + kk*384);
    float4 a0 = *(const float4*)&xt[kk*XT_PAD + tm*8];
    float4 a1 = *(const float4*)&xt[kk*XT_PAD + tm*8 + 4];
    float av[8]={a0.x,a0.y,a0.z,a0.w,a1.x,a1.y,a1.z,a1.w};
    #pragma unroll
    for(int i=0;i<8;i++){
      acc[i][0]=fmaf(av[i],w4.x,acc[i][0]);
      acc[i][1]=fmaf(av[i],w4.y,acc[i][1]);
      acc[i][2]=fmaf(av[i],w4.z,acc[i][2]);
      acc[i][3]=fmaf(av[i],w4.w,acc[i][3]);
    }
  }
  int n = nt*128 + tn*4;
  #pragma unroll
  for(int i=0;i<8;i++){
    size_t row = (size_t)(b*4096 + g0 + tm*8 + i);
    if(n < 192){
      *(float4*)(xp + row*192 + n) =
        make_float4(acc[i][0],acc[i][1],acc[i][2],acc[i][3]);
    } else {
      uint2 pz;
      pz.x = packbf2(acc[i][0],acc[i][1]);
      pz.y = packbf2(acc[i][2],acc[i][3]);
      *(uint2*)(z + row*192 + (n-192)) = pz;
    }
  }
}

// ---------------- K2: depthwise 3x3 conv + bias + silu (2x8 tile), bf16 out ----------------
__global__ __launch_bounds__(192) void k2_conv(
    const float* __restrict__ xp, const float* __restrict__ cw, const float* __restrict__ cb,
    __hip_bfloat16* __restrict__ xc)
{
  __shared__ float cw_s[1728];
  int tid = threadIdx.x;
  int pq = blockIdx.x, b = blockIdx.y;
  for(int i=tid;i<1728;i+=192) cw_s[i]=cw[i];
  __syncthreads();
  int th = (pq>>3)<<1;
  int tw = (pq&7)<<3;
  const float* base = xp + (size_t)b*4096*192 + tid;
  const float* wp = &cw_s[tid*9];
  float bias = cb[tid];
  float acc[2][8];
  #pragma unroll
  for(int r=0;r<2;r++)
    #pragma unroll
    for(int j=0;j<8;j++) acc[r][j]=bias;
  #pragma unroll
  for(int iy=0; iy<4; iy++){
    int hh = th-1+iy;
    if(hh<0||hh>63) continue;
    float v[10];
    #pragma unroll
    for(int xx=0;xx<10;xx++){
      int ww = tw-1+xx;
      v[xx] = (ww>=0 && ww<64) ? base[((size_t)(hh*64+ww))*192] : 0.f;
    }
    #pragma unroll
    for(int r=0;r<2;r++){
      int ky = iy - r;
      if(ky<0||ky>2) continue;
      float wk0=wp[ky*3], wk1=wp[ky*3+1], wk2=wp[ky*3+2];
      #pragma unroll
      for(int j=0;j<8;j++)
        acc[r][j] = fmaf(v[j],wk0, fmaf(v[j+1],wk1, fmaf(v[j+2],wk2, acc[r][j])));
    }
  }
  #pragma unroll
  for(int r=0;r<2;r++)
    #pragma unroll
    for(int j=0;j<8;j++){
      float a = acc[r][j];
      a = a * sigm(a);
      xc[((size_t)(b*4096) + (th+r)*64 + tw+j)*192 + tid] = __float2bfloat16(a);
    }
}

// ---------------- K3: x_proj GEMM (bf16 in via LDS) -> compact x_dbl ----------------
__global__ __launch_bounds__(320) void k3_proj(
    const __hip_bfloat16* __restrict__ xc, const float* __restrict__ xpwTp,
    float* __restrict__ xdbl)
{
  __shared__ float sm[32*192];
  int tid = threadIdx.x;
  int mt = blockIdx.x, b = blockIdx.y;
  int g0 = mt*32;
  const unsigned* xcb = (const unsigned*)(xc + ((size_t)(b*4096 + g0))*192);
  for(int idx=tid; idx<3072; idx+=320){
    unsigned u = xcb[idx];
    sm[idx*2]   = unpk_lo(u);
    sm[idx*2+1] = unpk_hi(u);
  }
  __syncthreads();
  int tn = tid%40, tm = tid/40;
  float acc[4][4];
  #pragma unroll
  for(int i=0;i<4;i++){acc[i][0]=0.f;acc[i][1]=0.f;acc[i][2]=0.f;acc[i][3]=0.f;}
  const float* wb = xpwTp + tn*4;
  for(int kk=0;kk<192;kk+=2){
    float4 w0 = *(const float4*)(wb + kk*160);
    float4 w1 = *(const float4*)(wb + (kk+1)*160);
    #pragma unroll
    for(int i=0;i<4;i++){
      float2 a = *(const float2*)&sm[(tm*4+i)*192 + kk];
      acc[i][0] = fmaf(a.x,w0.x, fmaf(a.y,w1.x, acc[i][0]));
      acc[i][1] = fmaf(a.x,w0.y, fmaf(a.y,w1.y, acc[i][1]));
      acc[i][2] = fmaf(a.x,w0.z, fmaf(a.y,w1.z, acc[i][2]));
      acc[i][3] = fmaf(a.x,w0.w, fmaf(a.y,w1.w, acc[i][3]));
    }
  }
  #pragma unroll
  for(int i=0;i<4;i++){
    *(float4*)(xdbl + ((size_t)(b*4096 + g0 + tm*4 + i))*160 + tn*4)
      = make_float4(acc[i][0],acc[i][1],acc[i][2],acc[i][3]);
  }
}

// ---------------- K4y: ONE local scan (h=0): y_loc + per-step S + chunk summaries ----------------
__global__ __launch_bounds__(192) void k4y_scan(
    const float* __restrict__ xdbl, const __hip_bfloat16* __restrict__ xc,
    const float* __restrict__ alog, const float* __restrict__ dtwT,
    const float* __restrict__ dtb, const float* __restrict__ Dsv,
    __hip_bfloat16* __restrict__ yB, __hip_bfloat16* __restrict__ Sst,
    __hip_bfloat16* __restrict__ localH, float* __restrict__ Ssum)
{
  int d = threadIdx.x;
  int ch = blockIdx.x, k = blockIdx.y, b = blockIdx.z;
  size_t prow = (size_t)b*4096;
  int p0, dp;
  scan_p0dp2(k, ch*CLEN, p0, dp);
  const float* rowp = xdbl + (prow + (size_t)p0)*160 + k*40;   // block-uniform
  ptrdiff_t rstride = (ptrdiff_t)dp*160;
  float w0=dtwT[(k*6+0)*192+d], w1=dtwT[(k*6+1)*192+d], w2=dtwT[(k*6+2)*192+d],
        w3=dtwT[(k*6+3)*192+d], w4=dtwT[(k*6+4)*192+d], w5=dtwT[(k*6+5)*192+d];
  float dtbv = dtb[k*192+d];
  float A0; bool fast1;
  {
    const float4* ap = (const float4*)(alog + (size_t)(k*192+d)*16);
    float4 a0=ap[0],a1=ap[1],a2=ap[2],a3=ap[3];
    float t[16]={a0.x,a0.y,a0.z,a0.w,a1.x,a1.y,a1.z,a1.w,a2.x,a2.y,a2.z,a2.w,a3.x,a3.y,a3.z,a3.w};
    A0 = -__expf(t[0]);
    bool fast = true;
    #pragma unroll
    for(int n=1;n<16;n++)
      fast = fast && (fabsf(-__expf(t[n]) - (float)(n+1)*A0) <= 1e-4f*(float)(n+1)*fabsf(A0));
    fast1 = fast && (A0 == -1.0f);
  }
  float dsv = Dsv[k*192+d];
  float S=0.f;
  const __hip_bfloat16* xu = xc + (prow + (size_t)p0)*192 + d;
  ptrdiff_t ustride = (ptrdiff_t)dp*192;
  size_t strm = (((size_t)(b*4+k))*4096 + ch*CLEN)*192 + d;
  __hip_bfloat16* yP = yB + strm;
  __hip_bfloat16* SP = Sst + strm;
  unsigned* lh = (unsigned*)(localH + ((((size_t)(b*4+k))*NCH + ch)*192 + d)*16);
  if(fast1){
    v2f h01={0.f,0.f},h23={0.f,0.f},h45={0.f,0.f},h67={0.f,0.f},
        h89={0.f,0.f},hAB={0.f,0.f},hCD={0.f,0.f},hEF={0.f,0.f};
    for(int i=0;i<CLEN;i++){
      const float* row = rowp; rowp += rstride;
      float u = __bfloat162float(*xu); xu += ustride;
      float4 r03 = *(const float4*)row;
      float2 r45 = *(const float2*)(row+4);
      float p01 = fmaf(r03.y,w1, r03.x*w0);
      float p23 = fmaf(r03.w,w3, r03.z*w2);
      float p45 = fmaf(r45.y,w5, r45.x*w4);
      float raw = (dtbv + p01) + (p23 + p45);
      float ex = __expf(raw);
      float tt = 1.f + ex;
      float delta = (raw>20.f)? raw : __logf(tt);
      float e1 = __builtin_amdgcn_rcpf(tt);     // e^{-delta} since A0=-1
      float du = delta*u;
      S += delta;
      SP[(size_t)i*192] = __float2bfloat16(S);
      float4 B0=*(const float4*)(row+8),  B1=*(const float4*)(row+12),
             B2=*(const float4*)(row+16), B3=*(const float4*)(row+20);
      float4 C0=*(const float4*)(row+24), C1=*(const float4*)(row+28),
             C2=*(const float4*)(row+32), C3=*(const float4*)(row+36);
      float e2s = e1*e1;
      v2f e2v = {e2s,e2s};
      v2f e4v = e2v*e2v;
      v2f e8v = e4v*e4v;
      v2f c01 = {e1,e2s};
      v2f c23 = c01*e2v;
      v2f c45 = c01*e4v;
      v2f c67 = c23*e4v;
      v2f c89 = c01*e8v;
      v2f cAB = c23*e8v;
      v2f cCD = c45*e8v;
      v2f cEF = c67*e8v;
      v2f du2 = {du,du};
      h01 = pkfma(h01,c01, du2*(v2f){B0.x,B0.y});
      h23 = pkfma(h23,c23, du2*(v2f){B0.z,B0.w});
      h45 = pkfma(h45,c45, du2*(v2f){B1.x,B1.y});
      h67 = pkfma(h67,c67, du2*(v2f){B1.z,B1.w});
      h89 = pkfma(h89,c89, du2*(v2f){B2.x,B2.y});
      hAB = pkfma(hAB,cAB, du2*(v2f){B2.z,B2.w});
      hCD = pkfma(hCD,cCD, du2*(v2f){B3.x,B3.y});
      hEF = pkfma(hEF,cEF, du2*(v2f){B3.z,B3.w});
      v2f yv = h01*(v2f){C0.x,C0.y};
      yv = pkfma(h23,(v2f){C0.z,C0.w}, yv);
      yv = pkfma(h45,(v2f){C1.x,C1.y}, yv);
      yv = pkfma(h67,(v2f){C1.z,C1.w}, yv);
      yv = pkfma(h89,(v2f){C2.x,C2.y}, yv);
      yv = pkfma(hAB,(v2f){C2.z,C2.w}, yv);
      yv = pkfma(hCD,(v2f){C3.x,C3.y}, yv);
      yv = pkfma(hEF,(v2f){C3.z,C3.w}, yv);
      yP[(size_t)i*192] = __float2bfloat16(fmaf(dsv, u, yv.x + yv.y));
    }
    uint4 q0, q1;
    q0.x = packbf2(h01.x,h01.y); q0.y = packbf2(h23.x,h23.y);
    q0.z = packbf2(h45.x,h45.y); q0.w = packbf2(h67.x,h67.y);
    q1.x = packbf2(h89.x,h89.y); q1.y = packbf2(hAB.x,hAB.y);
    q1.z = packbf2(hCD.x,hCD.y); q1.w = packbf2(hEF.x,hEF.y);
    *(uint4*)lh = q0;
    *(uint4*)(lh+4) = q1;
  } else {
    float A[16], h[16];
    {
      const float4* ap = (const float4*)(alog + (size_t)(k*192+d)*16);
      float4 a0=ap[0],a1=ap[1],a2=ap[2],a3=ap[3];
      float t[16]={a0.x,a0.y,a0.z,a0.w,a1.x,a1.y,a1.z,a1.w,a2.x,a2.y,a2.z,a2.w,a3.x,a3.y,a3.z,a3.w};
      #pragma unroll
      for(int n=0;n<16;n++){ A[n] = -__expf(t[n]); h[n]=0.f; }
    }
    for(int i=0;i<CLEN;i++){
      const float* row = rowp; rowp += rstride;
      float u = __bfloat162float(*xu); xu += ustride;
      float p01 = fmaf(row[1],w1, row[0]*w0);
      float p23 = fmaf(row[3],w3, row[2]*w2);
      float p45 = fmaf(row[5],w5, row[4]*w4);
      float delta = softplus_((dtbv + p01) + (p23 + p45));
      float du = delta*u;
      S += delta;
      SP[(size_t)i*192] = __float2bfloat16(S);
      float4 B0=*(const float4*)(row+8),  B1=*(const float4*)(row+12),
             B2=*(const float4*)(row+16), B3=*(const float4*)(row+20);
      float Bn[16]={B0.x,B0.y,B0.z,B0.w,B1.x,B1.y,B1.z,B1.w,
                    B2.x,B2.y,B2.z,B2.w,B3.x,B3.y,B3.z,B3.w};
      float4 C0=*(const float4*)(row+24), C1=*(const float4*)(row+28),
             C2=*(const float4*)(row+32), C3=*(const float4*)(row+36);
      float Cn[16]={C0.x,C0.y,C0.z,C0.w,C1.x,C1.y,C1.z,C1.w,
                    C2.x,C2.y,C2.z,C2.w,C3.x,C3.y,C3.z,C3.w};
      float y = 0.f;
      #pragma unroll
      for(int n=0;n<16;n++){
        h[n] = fmaf(h[n], __expf(delta*A[n]), du*Bn[n]);
        y = fmaf(h[n], Cn[n], y);
      }
      yP[(size_t)i*192] = __float2bfloat16(fmaf(dsv, u, y));
    }
    uint4 q0, q1;
    q0.x = packbf2(h[0],h[1]);   q0.y = packbf2(h[2],h[3]);
    q0.z = packbf2(h[4],h[5]);   q0.w = packbf2(h[6],h[7]);
    q1.x = packbf2(h[8],h[9]);   q1.y = packbf2(h[10],h[11]);
    q1.z = packbf2(h[12],h[13]); q1.w = packbf2(h[14],h[15]);
    *(uint4*)lh = q0;
    *(uint4*)(lh+4) = q1;
  }
  Ssum[(((size_t)(b*4+k))*NCH + ch)*192 + d] = S;
}

// ---------------- K4b: chain chunk states (bf16 lH; fp32 chain in regs) ----------------
__global__ __launch_bounds__(256) void k4b_chain(
    __hip_bfloat16* __restrict__ localH, const float* __restrict__ Ssum,
    const float* __restrict__ alog)
{
  int g = blockIdx.x*256 + threadIdx.x;   // 98304 = 32 bk * 3072 dn
  int bk = g/3072, dn = g - bk*3072;
  int k = bk & 3;
  int d = dn>>4, n = dn&15;
  float A = -__expf(alog[((size_t)(k*192+d))*16 + n]);
  size_t hbase = (size_t)bk*NCH*3072 + dn;
  size_t sbase = (size_t)bk*NCH*192 + d;
  float hv = 0.f;
  float loc = __bfloat162float(localH[hbase]);
  float S   = Ssum[sbase];
  for(int ch=0; ch<NCH; ch++){
    float nloc = 0.f, nS = 0.f;
    if(ch < NCH-1){
      nloc = __bfloat162float(localH[hbase + (size_t)(ch+1)*3072]);
      nS   = Ssum[sbase + (size_t)(ch+1)*192];
    }
    float dec = __expf(A*S);
    localH[hbase + (size_t)ch*3072] = __float2bfloat16(hv);
    hv = fmaf(hv, dec, loc);
    loc = nloc; S = nS;
  }
}

// ---------------- K4corr: y += C·(e^{A·S} ⊙ h0)  (skips chunk 0; early exit S>14) ----------------
__global__ __launch_bounds__(192) void k4corr(
    const float* __restrict__ xdbl, const float* __restrict__ alog,
    const __hip_bfloat16* __restrict__ hin, const __hip_bfloat16* __restrict__ Sst,
    __hip_bfloat16* __restrict__ yB)
{
  int d = threadIdx.x;
  int ch = blockIdx.x + 1, k = blockIdx.y, b = blockIdx.z;
  size_t prow = (size_t)b*4096;
  int p0, dp;
  scan_p0dp2(k, ch*CLEN, p0, dp);
  const float* rowp = xdbl + (prow + (size_t)p0)*160 + k*40 + 24;  // C base, uniform
  ptrdiff_t rstride = (ptrdiff_t)dp*160;
  float A0; bool fast1;
  {
    const float4* ap = (const float4*)(alog + (size_t)(k*192+d)*16);
    float4 a0=ap[0],a1=ap[1],a2=ap[2],a3=ap[3];
    float t[16]={a0.x,a0.y,a0.z,a0.w,a1.x,a1.y,a1.z,a1.w,a2.x,a2.y,a2.z,a2.w,a3.x,a3.y,a3.z,a3.w};
    A0 = -__expf(t[0]);
    bool fast = true;
    #pragma unroll
    for(int n=1;n<16;n++)
      fast = fast && (fabsf(-__expf(t[n]) - (float)(n+1)*A0) <= 1e-4f*(float)(n+1)*fabsf(A0));
    fast1 = fast && (A0 == -1.0f);
  }
  const unsigned* hp = (const unsigned*)(hin + ((((size_t)(b*4+k))*NCH + ch)*192 + d)*16);
  uint4 q0 = *(const uint4*)hp;
  uint4 q1 = *(const uint4*)(hp+4);
  size_t strm = (((size_t)(b*4+k))*4096 + ch*CLEN)*192 + d;
  const __hip_bfloat16* SP = Sst + strm;
  __hip_bfloat16* yP = yB + strm;
  if(fast1){
    v2f t01={unpk_lo(q0.x),unpk_hi(q0.x)}, t23={unpk_lo(q0.y),unpk_hi(q0.y)},
        t45={unpk_lo(q0.z),unpk_hi(q0.z)}, t67={unpk_lo(q0.w),unpk_hi(q0.w)},
        t89={unpk_lo(q1.x),unpk_hi(q1.x)}, tAB={unpk_lo(q1.y),unpk_hi(q1.y)},
        tCD={unpk_lo(q1.z),unpk_hi(q1.z)}, tEF={unpk_lo(q1.w),unpk_hi(q1.w)};
    for(int i=0;i<CLEN;i++){
      const float* row = rowp; rowp += rstride;
      float S = __bfloat162float(SP[(size_t)i*192]);
      if(__all(S > 14.f)) break;     // remaining corr < 1e-5, below bf16-y quantum
      float g = __expf(-S);
      float4 C0=*(const float4*)row,     C1=*(const float4*)(row+4),
             C2=*(const float4*)(row+8), C3=*(const float4*)(row+12);
      float g2s = g*g;
      v2f g2v = {g2s,g2s};
      v2f g4v = g2v*g2v;
      v2f g8v = g4v*g4v;
      v2f c01 = {g,g2s};
      v2f c23 = c01*g2v;
      v2f c45 = c01*g4v;
      v2f c67 = c23*g4v;
      v2f c89 = c01*g8v;
      v2f cAB = c23*g8v;
      v2f cCD = c45*g8v;
      v2f cEF = c67*g8v;
      v2f acc = t01*(c01*(v2f){C0.x,C0.y});
      acc = pkfma(t23, c23*(v2f){C0.z,C0.w}, acc);
      acc = pkfma(t45, c45*(v2f){C1.x,C1.y}, acc);
      acc = pkfma(t67, c67*(v2f){C1.z,C1.w}, acc);
      acc = pkfma(t89, c89*(v2f){C2.x,C2.y}, acc);
      acc = pkfma(tAB, cAB*(v2f){C2.z,C2.w}, acc);
      acc = pkfma(tCD, cCD*(v2f){C3.x,C3.y}, acc);
      acc = pkfma(tEF, cEF*(v2f){C3.z,C3.w}, acc);
      float corr = acc.x + acc.y;
      yP[(size_t)i*192] =
        __float2bfloat16(__bfloat162float(yP[(size_t)i*192]) + corr);
    }
  } else {
    float A[16], t[16];
    {
      const float4* ap = (const float4*)(alog + (size_t)(k*192+d)*16);
      float4 a0=ap[0],a1=ap[1],a2=ap[2],a3=ap[3];
      float tt[16]={a0.x,a0.y,a0.z,a0.w,a1.x,a1.y,a1.z,a1.w,a2.x,a2.y,a2.z,a2.w,a3.x,a3.y,a3.z,a3.w};
      #pragma unroll
      for(int n=0;n<16;n++) A[n] = -__expf(tt[n]);
    }
    t[0]=unpk_lo(q0.x); t[1]=unpk_hi(q0.x); t[2]=unpk_lo(q0.y); t[3]=unpk_hi(q0.y);
    t[4]=unpk_lo(q0.z); t[5]=unpk_hi(q0.z); t[6]=unpk_lo(q0.w); t[7]=unpk_hi(q0.w);
    t[8]=unpk_lo(q1.x); t[9]=unpk_hi(q1.x); t[10]=unpk_lo(q1.y); t[11]=unpk_hi(q1.y);
    t[12]=unpk_lo(q1.z); t[13]=unpk_hi(q1.z); t[14]=unpk_lo(q1.w); t[15]=unpk_hi(q1.w);
    for(int i=0;i<CLEN;i++){
      const float* row = rowp; rowp += rstride;
      float S = __bfloat162float(SP[(size_t)i*192]);
      float corr = 0.f;
      #pragma unroll
      for(int n=0;n<16;n++)
        corr = fmaf(t[n]*row[n], __expf(A[n]*S), corr);
      yP[(size_t)i*192] =
        __float2bfloat16(__bfloat162float(yP[(size_t)i*192]) + corr);
    }
  }
}

// ---------------- K5: combine + out_norm + silu(z) + out_proj + resid ----------------
#define YPAD 193
__global__ __launch_bounds__(256) void k5_combine(
    const __hip_bfloat16* __restrict__ yS, const __hip_bfloat16* __restrict__ z,
    const float* __restrict__ xT,
    const float* __restrict__ onw, const float* __restrict__ onb,
    const float* __restrict__ opwT, float* __restrict__ out_pre)
{
  __shared__ float yn[64*YPAD];
  __shared__ float wsm[48*96];
  __shared__ float mu_s[64], rs_s[64];
  int tid = threadIdx.x;
  int mt = blockIdx.x, b = blockIdx.y;
  int g0 = mt*64;
  size_t base = (size_t)b*4*4096;
  for(int idx=tid; idx<12288; idx+=256){
    int p = idx/192, d = idx - p*192;
    int gp = g0 + p;
    int l1 = ((gp&63)<<6)|(gp>>6);
    float v = __bfloat162float(yS[(base + gp)*192 + d])
            + __bfloat162float(yS[(base + 4096 + l1)*192 + d])
            + __bfloat162float(yS[(base + 2*4096 + (4095-gp))*192 + d])
            + __bfloat162float(yS[(base + 3*4096 + (4095-l1))*192 + d]);
    yn[p*YPAD+d] = v;
  }
  __syncthreads();
  {
    int p = tid>>2, q = tid&3;
    float s=0.f, sq=0.f;
    for(int c=q;c<192;c+=4){ float v=yn[p*YPAD+c]; s+=v; sq=fmaf(v,v,sq); }
    s  += __shfl_xor(s,1);  sq += __shfl_xor(sq,1);
    s  += __shfl_xor(s,2);  sq += __shfl_xor(sq,2);
    if(q==0){
      float mu = s*(1.f/192.f);
      mu_s[p]=mu; rs_s[p]=rsqrtf(sq*(1.f/192.f)-mu*mu+1e-5f);
    }
  }
  __syncthreads();
  for(int idx=tid; idx<12288; idx+=256){
    int p = idx/192, d = idx - p*192;
    float zz = __bfloat162float(z[((size_t)(b*4096+g0+p))*192 + d]);
    float v = (yn[p*YPAD+d]-mu_s[p])*rs_s[p]*onw[d]+onb[d];
    yn[p*YPAD+d] = v * zz * sigm(zz);
  }
  __syncthreads();
  int tn = tid&15, tm = tid>>4;
  float acc[4][6];
  #pragma unroll
  for(int i=0;i<4;i++)
    #pragma unroll
    for(int j=0;j<6;j++) acc[i][j]=0.f;
  for(int kc=0; kc<4; kc++){
    for(int idx=tid; idx<4608; idx+=256) wsm[idx] = opwT[kc*4608 + idx];
    __syncthreads();
    for(int kk=0;kk<48;kk++){
      float a0 = yn[(tm*4+0)*YPAD + kc*48+kk];
      float a1 = yn[(tm*4+1)*YPAD + kc*48+kk];
      float a2 = yn[(tm*4+2)*YPAD + kc*48+kk];
      float a3 = yn[(tm*4+3)*YPAD + kc*48+kk];
      const float* wr = &wsm[kk*96 + tn*6];
      #pragma unroll
      for(int j=0;j<6;j++){
        float w = wr[j];
        acc[0][j]=fmaf(a0,w,acc[0][j]);
        acc[1][j]=fmaf(a1,w,acc[1][j]);
        acc[2][j]=fmaf(a2,w,acc[2][j]);
        acc[3][j]=fmaf(a3,w,acc[3][j]);
      }
    }
    __syncthreads();
  }
  #pragma unroll
  for(int i=0;i<4;i++){
    size_t row = (size_t)(b*4096 + g0 + tm*4 + i);
    const float* xr = xT + row*96 + tn*6;
    float* orr = out_pre + row*96 + tn*6;
    #pragma unroll
    for(int j=0;j<6;j++) orr[j] = acc[i][j] + xr[j];
  }
}

// ---------------- K6: patch merge + LN + pm_red ----------------
__global__ __launch_bounds__(192) void k6_pm(
    const float* __restrict__ out_pre, const float* __restrict__ pmw, const float* __restrict__ pmb,
    const float* __restrict__ pmwT, float* __restrict__ outp)
{
  __shared__ float xm[8*388];
  __shared__ float xo[8*193];
  __shared__ float mus[8], rss[8];
  int tid = threadIdx.x;
  int jt = blockIdx.x, i = blockIdx.y, b = blockIdx.z;
  for(int idx=tid; idx<3072; idx+=192){
    int pj = idx/384, n = idx - pj*384;
    int q = n/96, c = n - q*96;
    int j = jt*8 + pj;
    int h2 = 2*i + (q&1), w2 = 2*j + (q>>1);
    xm[pj*388+n] = out_pre[((size_t)b*4096 + h2*64 + w2)*96 + c];
  }
  __syncthreads();
  if(tid<8){
    float s=0.f,q=0.f;
    for(int n=0;n<384;n++){ float v=xm[tid*388+n]; s+=v; q+=v*v; }
    float mu=s*(1.f/384.f);
    mus[tid]=mu; rss[tid]=rsqrtf(q*(1.f/384.f)-mu*mu+1e-5f);
  }
  __syncthreads();
  for(int idx=tid; idx<3072; idx+=192){
    int pj = idx/384, n = idx - pj*384;
    xm[pj*388+n] = (xm[pj*388+n]-mus[pj])*rss[pj]*pmw[n]+pmb[n];
  }
  __syncthreads();
  float acc[8];
  #pragma unroll
  for(int pj=0;pj<8;pj++) acc[pj]=0.f;
  const float* wb = pmwT + tid;
  for(int n4=0;n4<96;n4++){
    float w0=wb[(n4*4+0)*192], w1=wb[(n4*4+1)*192], w2=wb[(n4*4+2)*192], w3=wb[(n4*4+3)*192];
    #pragma unroll
    for(int pj=0;pj<8;pj++){
      float4 v = *(const float4*)&xm[pj*388 + n4*4];
      acc[pj] = fmaf(v.x,w0,fmaf(v.y,w1,fmaf(v.z,w2,fmaf(v.w,w3,acc[pj]))));
    }
  }
  #pragma unroll
  for(int pj=0;pj<8;pj++) xo[pj*193+tid]=acc[pj];
  __syncthreads();
  for(int idx=tid; idx<1536; idx+=192){
    int c2 = idx>>3, pj = idx&7;
    outp[(((size_t)b*192 + c2)*32 + i)*32 + jt*8 + pj] = xo[pj*193+c2];
  }
}

extern "C" void kernel_launch(void* const* d_in, const int* in_sizes, int n_in,
                              void* d_out, int out_size, void* d_ws, size_t ws_size,
                              hipStream_t stream)
{
  const float* x    = (const float*)d_in[0];
  const float* lnw  = (const float*)d_in[1];
  const float* lnb  = (const float*)d_in[2];
  const float* ipw  = (const float*)d_in[3];
  const float* cw   = (const float*)d_in[4];
  const float* cb   = (const float*)d_in[5];
  const float* xpw  = (const float*)d_in[6];
  const float* dtw  = (const float*)d_in[7];
  const float* dtb  = (const float*)d_in[8];
  const float* alog = (const float*)d_in[9];
  const float* Dsv  = (const float*)d_in[10];
  const float* onw  = (const float*)d_in[11];
  const float* onb  = (const float*)d_in[12];
  const float* opw  = (const float*)d_in[13];
  const float* pmnw = (const float*)d_in[14];
  const float* pmnb = (const float*)d_in[15];
  const float* pmrw = (const float*)d_in[16];
  float* out = (float*)d_out;

  float* ws    = (float*)d_ws;
  float* xT    = ws;              // (B,L,96)    3,145,728 f
  float* xpb   = xT + 3145728;    // (B,L,192)   6,291,456 f ; aliased: xdbl (k3..k4corr), out_pre (k5..k6)
  float* zbf   = xpb + 6291456;   // (B,L,192) bf16 -> 3,145,728 f-slots
  float* xcf   = zbf + 3145728;   // (B,L,192) bf16 -> 3,145,728 f-slots
  float* yBf   = xcf + 3145728;   // (B,K,L,192) bf16 -> 12,582,912 f-slots
  float* Sstf  = yBf + 12582912;  // (B,K,L,192) bf16 -> 12,582,912 f-slots
  float* lHf   = Sstf + 12582912; // (B,K,NCH,192,16) bf16 -> 3,145,728 f-slots
  float* Ss    = lHf + 3145728;   // (B,K,NCH,192)      393,216 f
  float* ipwT  = Ss + 393216;     // 36864
  float* xpwTp = ipwT + 36864;    // 30720
  float* dtwT  = xpwTp + 30720;   // 4608
  float* opwT  = dtwT + 4608;     // 18432
  float* pmwT  = opwT + 18432;    // 73728  -> total ~174 MiB
  float* xdbl  = xpb;             // (B,L,160) alias (conv-input dead after k2)
  float* outp  = xpb;             // out_pre alias (xdbl dead after k4corr)
  __hip_bfloat16* zb  = (__hip_bfloat16*)zbf;
  __hip_bfloat16* xc  = (__hip_bfloat16*)xcf;
  __hip_bfloat16* yB  = (__hip_bfloat16*)yBf;
  __hip_bfloat16* Sst = (__hip_bfloat16*)Sstf;
  __hip_bfloat16* lH  = (__hip_bfloat16*)lHf;

  k0_prep      <<<dim3(642),       dim3(256), 0, stream>>>(ipw,xpw,dtw,opw,pmrw, ipwT,xpwTp,dtwT,opwT,pmwT);
  k1_ln_inproj <<<dim3(64,3,8),    dim3(256), 0, stream>>>(x,lnw,lnb,ipwT, xT,xpb,zb);
  k2_conv      <<<dim3(256,8),     dim3(192), 0, stream>>>(xpb,cw,cb, xc);
  k3_proj      <<<dim3(128,8),     dim3(320), 0, stream>>>(xc,xpwTp, xdbl);
  k4y_scan     <<<dim3(NCH,4,8),   dim3(192), 0, stream>>>(xdbl,xc,alog,dtwT,dtb,Dsv, yB,Sst,lH,Ss);
  k4b_chain    <<<dim3(384),       dim3(256), 0, stream>>>(lH,Ss,alog);
  k4corr       <<<dim3(NCH-1,4,8), dim3(192), 0, stream>>>(xdbl,alog,lH,Sst, yB);
  k5_combine   <<<dim3(64,8),      dim3(256), 0, stream>>>(yB,zb,xT,onw,onb,opwT, outp);
  k6_pm        <<<dim3(4,32,8),    dim3(192), 0, stream>>>(outp,pmnw,pmnb,pmwT, out);
}